// Round 8
// baseline (41398.929 us; speedup 1.0000x reference)
//
#include <hip/hip_runtime.h>
#include <hip/hip_cooperative_groups.h>
#include <stdint.h>

namespace cg = cooperative_groups;

#define NPTS 1024
#define NDRAWS 20
#define NSTEPS 10
#define NG 100
#define PARTITIONABLE 1

#define TRI(i) (((i) * ((i) + 1)) / 2)
#define NTRI 136                      // 16*17/2
#define AST ((size_t)NTRI * 4096)     // floats per packed lower-tri matrix

typedef unsigned int u32;

// ---------------- threefry2x32 (JAX-compatible, 20 rounds) ----------------
__host__ __device__ static inline void tf2x32(u32 k0, u32 k1, u32 x0, u32 x1, u32* o0, u32* o1){
  u32 ks2 = k0 ^ k1 ^ 0x1BD11BDAu;
  x0 += k0; x1 += k1;
#define TFR(r) { x0 += x1; x1 = (x1 << r) | (x1 >> (32 - r)); x1 ^= x0; }
  TFR(13) TFR(15) TFR(26) TFR(6)
  x0 += k1; x1 += ks2 + 1u;
  TFR(17) TFR(29) TFR(16) TFR(24)
  x0 += ks2; x1 += k0 + 2u;
  TFR(13) TFR(15) TFR(26) TFR(6)
  x0 += k0; x1 += k1 + 3u;
  TFR(17) TFR(29) TFR(16) TFR(24)
  x0 += k1; x1 += ks2 + 4u;
  TFR(13) TFR(15) TFR(26) TFR(6)
  x0 += ks2; x1 += k0 + 5u;
#undef TFR
  *o0 = x0; *o1 = x1;
}

__device__ static inline u32 rand32(u32 ka, u32 kb, u32 i, u32 total){
  u32 a, b;
#if PARTITIONABLE
  (void)total;
  tf2x32(ka, kb, 0u, i, &a, &b);
  return a ^ b;
#else
  u32 h = total >> 1;
  if (i < h){ tf2x32(ka, kb, i, i + h, &a, &b); return a; }
  else      { tf2x32(ka, kb, i - h, i, &a, &b); return b; }
#endif
}

__device__ static inline float u01f(u32 bits){
  return __uint_as_float(0x3F800000u | (bits >> 9)) - 1.0f;
}

// XLA ErfInv32 (Giles) polynomial
__device__ static inline float erfinv32(float x){
  float w = -log1pf(-x * x);
  float p;
  if (w < 5.0f){
    w -= 2.5f;
    p = 2.81022636e-08f;
    p = fmaf(p, w, 3.43273939e-07f);
    p = fmaf(p, w, -3.5233877e-06f);
    p = fmaf(p, w, -4.39150654e-06f);
    p = fmaf(p, w, 0.00021858087f);
    p = fmaf(p, w, -0.00125372503f);
    p = fmaf(p, w, -0.00417768164f);
    p = fmaf(p, w, 0.246640727f);
    p = fmaf(p, w, 1.50140941f);
  } else {
    w = sqrtf(w) - 3.0f;
    p = -0.000200214257f;
    p = fmaf(p, w, 0.000100950558f);
    p = fmaf(p, w, 0.00134934322f);
    p = fmaf(p, w, -0.00367342844f);
    p = fmaf(p, w, 0.00573950773f);
    p = fmaf(p, w, -0.0076224613f);
    p = fmaf(p, w, 0.00943887047f);
    p = fmaf(p, w, 1.00167406f);
    p = fmaf(p, w, 2.83297682f);
  }
  return p * x;
}

__device__ static inline float normal_from_bits(u32 bits){
  const float LO = -0.99999994f;
  float u = u01f(bits);
  float v = u * 2.0f + LO;
  v = fmaxf(LO, v);
  return 1.4142135623730951f * erfinv32(v);
}

__device__ inline float  tsqrt(float x){ return sqrtf(x); }
__device__ inline double tsqrt(double x){ return sqrt(x); }
__device__ inline float  tmax(float a, float b){ return fmaxf(a, b); }
__device__ inline double tmax(double a, double b){ return fmax(a, b); }

__device__ inline void tri_decode(int p, int& ti, int& tj){
  int t = (int)((sqrtf(8.0f * (float)p + 1.0f) - 1.0f) * 0.5f);
  while ((t + 1) * (t + 2) / 2 <= p) ++t;
  while (t * (t + 1) / 2 > p) --t;
  ti = t; tj = p - t * (t + 1) / 2;
}

// interleaved right-looking chol + trinv of a 64x64 tile in LDS (256 threads)
template<typename T, int S>
__device__ inline void chol_inv_64t(T* t, T* Xs, T* diagL, int tid){
  for (int idx = tid; idx < 4096; idx += 256){
    int r = idx >> 6, c = idx & 63;
    Xs[r * S + c] = (r == c) ? (T)1 : (T)0;
  }
  __syncthreads();
  for (int j = 0; j < 64; ++j){
    T piv = tsqrt(tmax(t[j * S + j], (T)1e-30));
    T inv = (T)1 / piv;
    if (tid < 64){
      int r = j + 1 + tid;
      if (r < 64) t[r * S + j] *= inv;
      if (tid == 0) diagL[j] = piv;
    } else if (tid < 128){
      Xs[j * S + (tid - 64)] *= inv;
    }
    __syncthreads();
    int tg = tid >> 6, tr = tid & 63;
    for (int r2 = j + 1 + tg; r2 < 64; r2 += 4){
      T lj = t[r2 * S + j];
      int c = j + 1 + tr;
      if (c <= r2) t[r2 * S + c] -= lj * t[c * S + j];
      Xs[r2 * S + tr] = Xs[r2 * S + tr] - lj * Xs[j * S + tr];
    }
    __syncthreads();
  }
  if (tid < 64) t[tid * S + tid] = diagL[tid];
  __syncthreads();
}

// ---------------- setup kernels ----------------
__global__ __launch_bounds__(256) void k_prep(const float* X, const int* Y, float* x2, float* kappaf){
  int n = blockIdx.x * 256 + threadIdx.x;
  if (n >= NPTS) return;
  float s = 0.f;
  for (int d = 0; d < 64; ++d){ float v = X[n * 64 + d]; s += v * v; }
  x2[n] = s;
  kappaf[NPTS - 1 - n] = (float)Y[n] - 0.5f;
}

__global__ void k_computeK(const float* X, const float* x2, const float* osp, const float* lsp,
                           double* Ld){
  int j = blockIdx.x * 16 + threadIdx.x;
  int i = blockIdx.y * 16 + threadIdx.y;
  float os = osp[0], ls = lsp[0];
  float dot = 0.f;
  for (int d = 0; d < 64; ++d) dot += X[i * 64 + d] * X[j * 64 + d];
  float d2 = x2[i] + x2[j] - 2.0f * dot;
  d2 = fmaxf(d2, 0.0f);
  float kv = os * expf((-0.5f * d2) / (ls * ls));
  Ld[(size_t)i * NPTS + j] = (double)kv + (i == j ? 1e-6 : 0.0);
}

__global__ __launch_bounds__(256) void k_castL(const double* Ld, float* Lf){
  int idx = blockIdx.x * 256 + threadIdx.x;
  int i = idx >> 10, j = idx & 1023;
  Lf[idx] = (j <= i) ? (float)Ld[idx] : 0.0f;
}

__global__ __launch_bounds__(256) void k_logdetK(const double* Ld, float* ldetK){
  __shared__ double red[4];
  int tid = threadIdx.x;
  double s = 0.0;
  for (int i = tid; i < NPTS; i += 256) s += log(Ld[(size_t)i * NPTS + i]);
  for (int o = 32; o; o >>= 1) s += __shfl_down(s, o);
  if ((tid & 63) == 0) red[tid >> 6] = s;
  __syncthreads();
  if (tid == 0) ldetK[0] = (float)(2.0 * (red[0] + red[1] + red[2] + red[3]));
}

// ---------------- f64 dense blocked Cholesky (setup only) ----------------
__global__ __launch_bounds__(256) void k_chol_diag_inv_d(double* M, double* Dinv, int p){
  double* DI = Dinv + (size_t)p * 4096;
  int k0 = p * 64;
  __shared__ double t[64][65];
  __shared__ double Xs[64][65];
  __shared__ double diagL[64];
  int tid = threadIdx.x;
  for (int idx = tid; idx < 4096; idx += 256){
    int r = idx >> 6, c = idx & 63;
    t[r][c] = (c <= r) ? M[(size_t)(k0 + r) * NPTS + k0 + c] : 0.0;
  }
  __syncthreads();
  chol_inv_64t<double, 65>(&t[0][0], &Xs[0][0], &diagL[0], tid);
  for (int idx = tid; idx < 4096; idx += 256){
    int r = idx >> 6, c = idx & 63;
    M[(size_t)(k0 + r) * NPTS + k0 + c] = (c <= r) ? t[r][c] : 0.0;
    DI[idx] = Xs[r][c];
  }
}

__global__ __launch_bounds__(256) void k_chol_panel_d(double* M, const double* Dinv, int p){
  const double* DI = Dinv + (size_t)p * 4096;
  int r0 = (p + 1) * 64 + blockIdx.x * 64;
  __shared__ double Rs[64][65];
  __shared__ double Ds[64][65];
  int tid = threadIdx.x;
  for (int idx = tid; idx < 4096; idx += 256){
    int r = idx >> 6, c = idx & 63;
    Rs[r][c] = M[(size_t)(r0 + r) * NPTS + p * 64 + c];
    Ds[r][c] = DI[idx];
  }
  __syncthreads();
  int tx = tid & 15, ty = tid >> 4;
  double acc[4][4];
#pragma unroll
  for (int a = 0; a < 4; ++a)
#pragma unroll
    for (int b = 0; b < 4; ++b) acc[a][b] = 0.0;
  for (int k = 0; k < 64; ++k){
    double av[4], bv[4];
#pragma unroll
    for (int a = 0; a < 4; ++a) av[a] = Rs[ty * 4 + a][k];
#pragma unroll
    for (int b = 0; b < 4; ++b) bv[b] = Ds[tx * 4 + b][k];
#pragma unroll
    for (int a = 0; a < 4; ++a)
#pragma unroll
      for (int b = 0; b < 4; ++b) acc[a][b] += av[a] * bv[b];
  }
#pragma unroll
  for (int a = 0; a < 4; ++a)
#pragma unroll
    for (int b = 0; b < 4; ++b)
      M[(size_t)(r0 + ty * 4 + a) * NPTS + p * 64 + tx * 4 + b] = acc[a][b];
}

__global__ __launch_bounds__(256) void k_chol_update_d(double* M, int k0){
  __shared__ double Pa[64][65];
  __shared__ double Pb[64][65];
  int ti, tj; tri_decode(blockIdx.x, ti, tj);
  int bi = k0 + 64 + ti * 64;
  int bj = k0 + 64 + tj * 64;
  int tid = threadIdx.x;
  for (int idx = tid; idx < 4096; idx += 256){
    int r = idx >> 6, c = idx & 63;
    Pa[r][c] = M[(size_t)(bi + r) * NPTS + k0 + c];
    Pb[r][c] = M[(size_t)(bj + r) * NPTS + k0 + c];
  }
  __syncthreads();
  int tx = tid & 15, ty = tid >> 4;
  double acc[4][4];
#pragma unroll
  for (int a = 0; a < 4; ++a)
#pragma unroll
    for (int b = 0; b < 4; ++b) acc[a][b] = 0.0;
  for (int k = 0; k < 64; ++k){
    double av[4], bv[4];
#pragma unroll
    for (int a = 0; a < 4; ++a) av[a] = Pa[ty * 4 + a][k];
#pragma unroll
    for (int b = 0; b < 4; ++b) bv[b] = Pb[tx * 4 + b][k];
#pragma unroll
    for (int a = 0; a < 4; ++a)
#pragma unroll
      for (int b = 0; b < 4; ++b) acc[a][b] += av[a] * bv[b];
  }
#pragma unroll
  for (int a = 0; a < 4; ++a)
#pragma unroll
    for (int b = 0; b < 4; ++b){
      int gi = bi + ty * 4 + a, gj = bj + tx * 4 + b;
      M[(size_t)gi * NPTS + gj] -= acc[a][b];
    }
}

static void run_chol_d(double* A, double* Dinv, hipStream_t s){
  for (int p = 0; p < 16; ++p){
    k_chol_diag_inv_d<<<dim3(1), 256, 0, s>>>(A, Dinv, p);
    int nrb = 15 - p;
    if (nrb > 0){
      k_chol_panel_d<<<dim3(nrb), 256, 0, s>>>(A, Dinv, p);
      k_chol_update_d<<<dim3(nrb * (nrb + 1) / 2), 256, 0, s>>>(A, p * 64);
    }
  }
}

// ---------------- f64 triangular inverse (one-time, for Kinv), slice-parallel ----------------
__global__ __launch_bounds__(256) void k_trinv_copy_diag(const double* DinvD, double* Td){
  int p = blockIdx.x;
  for (int idx = threadIdx.x; idx < 4096; idx += 256){
    int r = idx >> 6, c = idx & 63;
    Td[(size_t)(p * 64 + r) * NPTS + p * 64 + c] = DinvD[(size_t)p * 4096 + idx];
  }
}

__global__ __launch_bounds__(256) void k_trinv_part(const double* Lm, const double* Td,
                                                    double* Gs, int lev){
  int J = blockIdx.x, s = blockIdx.y;
  int I = J + lev, K = J + s;
  __shared__ double Ta[64][65];
  __shared__ double Tb[64][65];
  int tid = threadIdx.x, tx = tid & 15, ty = tid >> 4;
  for (int idx = tid; idx < 4096; idx += 256){
    int r = idx >> 6, c = idx & 63;
    Ta[r][c] = Lm[(size_t)(I * 64 + r) * NPTS + K * 64 + c];
    Tb[r][c] = Td[(size_t)(K * 64 + r) * NPTS + J * 64 + c];
  }
  __syncthreads();
  double acc[4][4];
#pragma unroll
  for (int a = 0; a < 4; ++a)
#pragma unroll
    for (int b = 0; b < 4; ++b) acc[a][b] = 0.0;
  for (int k = 0; k < 64; ++k){
    double av[4], bv[4];
#pragma unroll
    for (int a = 0; a < 4; ++a) av[a] = Ta[ty * 4 + a][k];
#pragma unroll
    for (int b = 0; b < 4; ++b) bv[b] = Tb[k][tx * 4 + b];
#pragma unroll
    for (int a = 0; a < 4; ++a)
#pragma unroll
      for (int b = 0; b < 4; ++b) acc[a][b] += av[a] * bv[b];
  }
  double* out = Gs + ((size_t)J * 15 + s) * 4096;
#pragma unroll
  for (int a = 0; a < 4; ++a)
#pragma unroll
    for (int b = 0; b < 4; ++b)
      out[(ty * 4 + a) * 64 + tx * 4 + b] = acc[a][b];
}

__global__ __launch_bounds__(256) void k_trinv_fin(double* Td, const double* Gs, int lev){
  int J = blockIdx.x, I = J + lev;
  __shared__ double Ta[64][65];
  __shared__ double Tb[64][65];
  int tid = threadIdx.x, tx = tid & 15, ty = tid >> 4;
  for (int idx = tid; idx < 4096; idx += 256){
    int r = idx >> 6, c = idx & 63;
    double g = 0.0;
    for (int s = 0; s < lev; ++s) g += Gs[((size_t)J * 15 + s) * 4096 + idx];
    Tb[r][c] = g;
    Ta[r][c] = Td[(size_t)(I * 64 + r) * NPTS + I * 64 + c];
  }
  __syncthreads();
  double ac2[4][4];
#pragma unroll
  for (int a = 0; a < 4; ++a)
#pragma unroll
    for (int b = 0; b < 4; ++b) ac2[a][b] = 0.0;
  for (int k = 0; k < 64; ++k){
    double av[4], bv[4];
#pragma unroll
    for (int a = 0; a < 4; ++a) av[a] = Ta[ty * 4 + a][k];
#pragma unroll
    for (int b = 0; b < 4; ++b) bv[b] = Tb[k][tx * 4 + b];
#pragma unroll
    for (int a = 0; a < 4; ++a)
#pragma unroll
      for (int b = 0; b < 4; ++b) ac2[a][b] += av[a] * bv[b];
  }
#pragma unroll
  for (int a = 0; a < 4; ++a)
#pragma unroll
    for (int b = 0; b < 4; ++b)
      Td[(size_t)(I * 64 + ty * 4 + a) * NPTS + J * 64 + tx * 4 + b] = -ac2[a][b];
}

__global__ __launch_bounds__(256) void k_syrk_kinv_flip(const double* Td, float* Kinvp){
  int a0, b0; tri_decode(blockIdx.x, a0, b0);   // a0 >= b0
  int ti = b0, tj = a0;                          // ti <= tj
  int kmin = tj;
  __shared__ double Ta[64][65];
  __shared__ double Tb[64][65];
  int tid = threadIdx.x, tx = tid & 15, ty = tid >> 4;
  double acc[4][4];
#pragma unroll
  for (int a = 0; a < 4; ++a)
#pragma unroll
    for (int b = 0; b < 4; ++b) acc[a][b] = 0.0;
  for (int K = kmin; K < 16; ++K){
    __syncthreads();
    for (int idx = tid; idx < 4096; idx += 256){
      int r = idx >> 6, c = idx & 63;
      Ta[r][c] = Td[(size_t)(K * 64 + r) * NPTS + ti * 64 + c];
      Tb[r][c] = Td[(size_t)(K * 64 + r) * NPTS + tj * 64 + c];
    }
    __syncthreads();
    for (int k = 0; k < 64; ++k){
      double av[4], bv[4];
#pragma unroll
      for (int a = 0; a < 4; ++a) av[a] = Ta[k][ty * 4 + a];
#pragma unroll
      for (int b = 0; b < 4; ++b) bv[b] = Tb[k][tx * 4 + b];
#pragma unroll
      for (int a = 0; a < 4; ++a)
#pragma unroll
        for (int b = 0; b < 4; ++b) acc[a][b] += av[a] * bv[b];
    }
  }
  int tileR = 15 - ti, tileC = 15 - tj;
  float* out = Kinvp + (size_t)(TRI(tileR) + tileC) * 4096;
#pragma unroll
  for (int a = 0; a < 4; ++a)
#pragma unroll
    for (int b = 0; b < 4; ++b){
      int rin = 63 - (ty * 4 + a), cin = 63 - (tx * 4 + b);
      out[rin * 64 + cin] = (float)acc[a][b];
    }
}

// ================= cooperative Gibbs-step phase functions =================

__device__ inline void ph_geneps(u32 ka, u32 kb, float* eps, int c0, int nb, int tid){
  int total = nb * NPTS;
  for (int b0 = blockIdx.x * 256; b0 < total; b0 += gridDim.x * 256){
    int i = b0 + tid;
    if (i < total){
      int g = c0 * NPTS + i;
      u32 bits = rand32(ka, kb, (u32)g, (u32)(NDRAWS * NPTS));
      eps[g] = normal_from_bits(bits);
    }
  }
}

__device__ inline void ph_pg(u32 ka, u32 kb, const float* f, float* omega, int c0, int nb, int tid){
  int total = nb * NPTS;
  for (int b0 = blockIdx.x * 256; b0 < total; b0 += gridDim.x * 256){
    int i = b0 + tid;
    if (i < total){
      int gidx = c0 * NPTS + i;
      float c = f[gidx];
      float c2w = (c * c) / 39.47841760435743f;
      float sum = 0.f;
      u32 base = (u32)gidx * NG;
      for (int g = 0; g < NG; ++g){
        u32 bits = rand32(ka, kb, base + (u32)g, (u32)(NDRAWS * NPTS * NG));
        float u = u01f(bits);
        float e = -log1pf(-u);
        float kk = (float)g + 0.5f;
        sum += e / (kk * kk + c2w);
      }
      omega[gidx] = sum / 19.739208802178716f;
    }
  }
}

__device__ inline void ph_buildA(const float* Kinvp, const float* omega, float* Ab,
                                 int c0, int nb, int clip, int tid){
  for (int task = blockIdx.x; task < 544 * nb; task += gridDim.x){
    int dd = task / 544, blk = task - dd * 544;
    int d = c0 + dd;
    float* A = Ab + (size_t)dd * AST;
    int idx4 = blk * 256 + tid;
    float4 v = ((const float4*)Kinvp)[idx4];
    int tile = idx4 >> 10;
    int ti, tj; tri_decode(tile, ti, tj);
    if (ti == tj){
      int e = (idx4 & 1023) * 4;
      int r = e >> 6, c = e & 63;
      if (c <= r && r < c + 4){
        float om = omega[(size_t)d * NPTS + (NPTS - 1 - (ti * 64 + r))];
        if (clip) om = fmaxf(om, 1e-16f);
        ((float*)&v)[r - c] += om;
      }
    }
    ((float4*)A)[idx4] = v;
  }
}

__device__ inline void ph_diag0(float* Ab, float* Dinv, int nb, int tid,
                                float* shT, float* shX, float* dgl){
  for (int task = blockIdx.x; task < nb; task += gridDim.x){
    float* M = Ab + (size_t)task * AST;
    float* DI = Dinv + (size_t)task * 16 * 4096;
    for (int idx = tid; idx < 1024; idx += 256){
      float4 v = ((const float4*)M)[idx];
      int e = idx * 4, r = e >> 6, c = e & 63;
      shT[r * 68 + c] = v.x; shT[r * 68 + c + 1] = v.y;
      shT[r * 68 + c + 2] = v.z; shT[r * 68 + c + 3] = v.w;
    }
    __syncthreads();
    chol_inv_64t<float, 68>(shT, shX, dgl, tid);
    for (int idx = tid; idx < 1024; idx += 256){
      int e = idx * 4, r = e >> 6, c = e & 63;
      float4 v, w;
      v.x = (c     <= r) ? shT[r * 68 + c]     : 0.f;
      v.y = (c + 1 <= r) ? shT[r * 68 + c + 1] : 0.f;
      v.z = (c + 2 <= r) ? shT[r * 68 + c + 2] : 0.f;
      v.w = (c + 3 <= r) ? shT[r * 68 + c + 3] : 0.f;
      w.x = shX[r * 68 + c]; w.y = shX[r * 68 + c + 1];
      w.z = shX[r * 68 + c + 2]; w.w = shX[r * 68 + c + 3];
      ((float4*)M)[idx] = v;
      ((float4*)DI)[idx] = w;
    }
    __syncthreads();
  }
}

__device__ inline void ph_panel(float* Ab, const float* Dinv, int p, int nb, int tid,
                                float* Rst, float* Dst){
  int nrb = 15 - p;
  int tx = tid & 15, ty = tid >> 4;
  for (int task = blockIdx.x; task < nrb * nb; task += gridDim.x){
    int dd = task / nrb, rto = task - dd * nrb;
    float* M = Ab + (size_t)dd * AST;
    const float* DI = Dinv + ((size_t)dd * 16 + p) * 4096;
    int rt = p + 1 + rto;
    float* R = M + (size_t)(TRI(rt) + p) * 4096;
    for (int idx = tid; idx < 1024; idx += 256){
      float4 v = ((const float4*)R)[idx];
      float4 w = ((const float4*)DI)[idx];
      int e = idx * 4, r = e >> 6, c = e & 63;
      Rst[(c + 0) * 68 + r] = v.x; Rst[(c + 1) * 68 + r] = v.y;
      Rst[(c + 2) * 68 + r] = v.z; Rst[(c + 3) * 68 + r] = v.w;
      Dst[(c + 0) * 68 + r] = w.x; Dst[(c + 1) * 68 + r] = w.y;
      Dst[(c + 2) * 68 + r] = w.z; Dst[(c + 3) * 68 + r] = w.w;
    }
    __syncthreads();
    float acc[4][4];
#pragma unroll
    for (int a = 0; a < 4; ++a)
#pragma unroll
      for (int b = 0; b < 4; ++b) acc[a][b] = 0.f;
    for (int k = 0; k < 64; ++k){
      float4 av4 = *(const float4*)&Rst[k * 68 + ty * 4];
      float4 bv4 = *(const float4*)&Dst[k * 68 + tx * 4];
      float av[4] = {av4.x, av4.y, av4.z, av4.w};
      float bv[4] = {bv4.x, bv4.y, bv4.z, bv4.w};
#pragma unroll
      for (int a = 0; a < 4; ++a)
#pragma unroll
        for (int b = 0; b < 4; ++b) acc[a][b] += av[a] * bv[b];
    }
#pragma unroll
    for (int a = 0; a < 4; ++a){
      float4 v;
      v.x = acc[a][0]; v.y = acc[a][1]; v.z = acc[a][2]; v.w = acc[a][3];
      *((float4*)&R[(size_t)(ty * 4 + a) * 64 + tx * 4]) = v;
    }
    __syncthreads();
  }
}

__device__ inline void ph_update(float* Ab, float* Dinv, int p, int nb, int tid,
                                 float* Pat, float* Pbt, float* dgl){
  int nrb = 15 - p;
  int ntri = nrb * (nrb + 1) / 2;
  int tx = tid & 15, ty = tid >> 4;
  for (int task = blockIdx.x; task < ntri * nb; task += gridDim.x){
    int dd = task / ntri, tri = task - dd * ntri;
    float* M = Ab + (size_t)dd * AST;
    int t0, t1; tri_decode(tri, t0, t1);
    int bi = p + 1 + t0, bj = p + 1 + t1;
    const float* La = M + (size_t)(TRI(bi) + p) * 4096;
    const float* Lb = M + (size_t)(TRI(bj) + p) * 4096;
    float* Atile = M + (size_t)(TRI(bi) + bj) * 4096;
    for (int idx = tid; idx < 1024; idx += 256){
      float4 v = ((const float4*)La)[idx];
      float4 w = ((const float4*)Lb)[idx];
      int e = idx * 4, r = e >> 6, c = e & 63;
      Pat[(c + 0) * 68 + r] = v.x; Pat[(c + 1) * 68 + r] = v.y;
      Pat[(c + 2) * 68 + r] = v.z; Pat[(c + 3) * 68 + r] = v.w;
      Pbt[(c + 0) * 68 + r] = w.x; Pbt[(c + 1) * 68 + r] = w.y;
      Pbt[(c + 2) * 68 + r] = w.z; Pbt[(c + 3) * 68 + r] = w.w;
    }
    __syncthreads();
    float acc[4][4];
#pragma unroll
    for (int a = 0; a < 4; ++a)
#pragma unroll
      for (int b = 0; b < 4; ++b) acc[a][b] = 0.f;
    for (int k = 0; k < 64; ++k){
      float4 av4 = *(const float4*)&Pat[k * 68 + ty * 4];
      float4 bv4 = *(const float4*)&Pbt[k * 68 + tx * 4];
      float av[4] = {av4.x, av4.y, av4.z, av4.w};
      float bv[4] = {bv4.x, bv4.y, bv4.z, bv4.w};
#pragma unroll
      for (int a = 0; a < 4; ++a)
#pragma unroll
        for (int b = 0; b < 4; ++b) acc[a][b] += av[a] * bv[b];
    }
    if (tri == 0){
      __syncthreads();
      for (int idx = tid; idx < 1024; idx += 256){
        float4 v = ((const float4*)Atile)[idx];
        int e = idx * 4, r = e >> 6, c = e & 63;
        Pat[r * 68 + c] = v.x; Pat[r * 68 + c + 1] = v.y;
        Pat[r * 68 + c + 2] = v.z; Pat[r * 68 + c + 3] = v.w;
      }
      __syncthreads();
#pragma unroll
      for (int a = 0; a < 4; ++a)
#pragma unroll
        for (int b = 0; b < 4; ++b)
          Pat[(ty * 4 + a) * 68 + tx * 4 + b] -= acc[a][b];
      __syncthreads();
      chol_inv_64t<float, 68>(Pat, Pbt, dgl, tid);
      float* DI = Dinv + ((size_t)dd * 16 + (p + 1)) * 4096;
      for (int idx = tid; idx < 1024; idx += 256){
        int e = idx * 4, r = e >> 6, c = e & 63;
        float4 v, w;
        v.x = (c     <= r) ? Pat[r * 68 + c]     : 0.f;
        v.y = (c + 1 <= r) ? Pat[r * 68 + c + 1] : 0.f;
        v.z = (c + 2 <= r) ? Pat[r * 68 + c + 2] : 0.f;
        v.w = (c + 3 <= r) ? Pat[r * 68 + c + 3] : 0.f;
        w.x = Pbt[r * 68 + c]; w.y = Pbt[r * 68 + c + 1];
        w.z = Pbt[r * 68 + c + 2]; w.w = Pbt[r * 68 + c + 3];
        ((float4*)Atile)[idx] = v;
        ((float4*)DI)[idx] = w;
      }
      __syncthreads();
    } else {
#pragma unroll
      for (int a = 0; a < 4; ++a){
        float4 v = *((const float4*)&Atile[(size_t)(ty * 4 + a) * 64 + tx * 4]);
        v.x -= acc[a][0]; v.y -= acc[a][1]; v.z -= acc[a][2]; v.w -= acc[a][3];
        *((float4*)&Atile[(size_t)(ty * 4 + a) * 64 + tx * 4]) = v;
      }
      __syncthreads();
    }
  }
}

__device__ inline void ph_solve(const float* Ab, const float* DinvF, const float* kappaf,
                                const float* eps, float* fbuf, int c0, int nb, int tid,
                                float* smem){
  float* z1  = smem;
  float* z2  = smem + 1024;
  float* bufp = smem + 2048;          // 2 x 4160
  float* pr1 = smem + 10368;          // 4 x 64
  float* pr2 = smem + 10624;          // 4 x 64
  for (int task = blockIdx.x; task < nb; task += gridDim.x){
    int d0 = task, d = c0 + task;
    const float* L = Ab + (size_t)d0 * AST;
    const float* DI = DinvF + (size_t)d0 * 16 * 4096;
    float4 rg[4];
    auto loadDI = [&](int p){
#pragma unroll
      for (int j = 0; j < 4; ++j)
        rg[j] = *(const float4*)&DI[p * 4096 + j * 1024 + tid * 4];
    };
    auto loadL = [&](int row, int col){
      const float* T = L + (size_t)(TRI(row) + col) * 4096;
#pragma unroll
      for (int j = 0; j < 4; ++j)
        rg[j] = *(const float4*)&T[j * 1024 + tid * 4];
    };
    auto store = [&](int cur){
#pragma unroll
      for (int j = 0; j < 4; ++j){
        int e = j * 1024 + tid * 4; int r = e >> 6, c = e & 63;
        float* b = &bufp[cur * 4160 + r * 65 + c];
        b[0] = rg[j].x; b[1] = rg[j].y; b[2] = rg[j].z; b[3] = rg[j].w;
      }
    };
    for (int i = tid; i < NPTS; i += 256){
      z1[i] = kappaf[i];
      z2[NPTS - 1 - i] = eps[(size_t)d * NPTS + i];
    }
    loadDI(0);
    int cur = 0;
    for (int p = 0; p < 16; ++p){
      for (int rb = p; rb < 16; ++rb){
        store(cur);
        int np = p, nr2 = rb + 1;
        if (nr2 >= 16){ np = p + 1; nr2 = np; }
        if (np < 16){ if (nr2 == np) loadDI(np); else loadL(nr2, np); }
        __syncthreads();
        int rr = tid & 63, q = tid >> 6;
        float s = 0.f;
#pragma unroll
        for (int cc = 0; cc < 16; ++cc)
          s += bufp[cur * 4160 + rr * 65 + q * 16 + cc] * z1[p * 64 + q * 16 + cc];
        pr1[q * 64 + rr] = s;
        __syncthreads();
        if (tid < 64){
          float v = pr1[tid] + pr1[64 + tid] + pr1[128 + tid] + pr1[192 + tid];
          if (rb == p) z1[p * 64 + tid] = v;
          else z1[rb * 64 + tid] -= v;
        }
        __syncthreads();
        cur ^= 1;
      }
    }
    loadDI(15);
    for (int p = 15; p >= 0; --p){
      for (int cb = p; cb >= 0; --cb){
        store(cur);
        int np = p, ncb = cb - 1;
        if (ncb < 0){ np = p - 1; ncb = np; }
        if (np >= 0){ if (ncb == np) loadDI(np); else loadL(np, ncb); }
        __syncthreads();
        int cc2 = tid & 63, q = tid >> 6;
        float s1 = 0.f, s2 = 0.f;
#pragma unroll
        for (int rr = 0; rr < 16; ++rr){
          float t = bufp[cur * 4160 + (q * 16 + rr) * 65 + cc2];
          s1 += t * z1[p * 64 + q * 16 + rr];
          s2 += t * z2[p * 64 + q * 16 + rr];
        }
        pr1[q * 64 + cc2] = s1; pr2[q * 64 + cc2] = s2;
        __syncthreads();
        if (tid < 64){
          float v1 = pr1[tid] + pr1[64 + tid] + pr1[128 + tid] + pr1[192 + tid];
          float v2 = pr2[tid] + pr2[64 + tid] + pr2[128 + tid] + pr2[192 + tid];
          if (cb == p){ z1[p * 64 + tid] = v1; z2[p * 64 + tid] = v2; }
          else { z1[cb * 64 + tid] -= v1; z2[cb * 64 + tid] -= v2; }
        }
        __syncthreads();
        cur ^= 1;
      }
    }
    for (int i = tid; i < NPTS; i += 256)
      fbuf[(size_t)d * NPTS + i] = z1[NPTS - 1 - i] + z2[NPTS - 1 - i];
    __syncthreads();
  }
}

__device__ inline void ph_final(const float* Ab, const float* DinvF, const float* kappaf,
                                const float* ldetK, float* mll, int c0, int nb, int tid,
                                float* smem){
  float* z    = smem;
  float* bufp = smem + 2048;
  float* part = smem + 10368;
  float* redq = smem + 10624;
  for (int task = blockIdx.x; task < nb; task += gridDim.x){
    int d0 = task, d = c0 + task;
    const float* L = Ab + (size_t)d0 * AST;
    const float* DI = DinvF + (size_t)d0 * 16 * 4096;
    float4 rg[4];
    auto loadDI = [&](int p){
#pragma unroll
      for (int j = 0; j < 4; ++j)
        rg[j] = *(const float4*)&DI[p * 4096 + j * 1024 + tid * 4];
    };
    auto loadL = [&](int row, int col){
      const float* T = L + (size_t)(TRI(row) + col) * 4096;
#pragma unroll
      for (int j = 0; j < 4; ++j)
        rg[j] = *(const float4*)&T[j * 1024 + tid * 4];
    };
    auto store = [&](int cur){
#pragma unroll
      for (int j = 0; j < 4; ++j){
        int e = j * 1024 + tid * 4; int r = e >> 6, c = e & 63;
        float* b = &bufp[cur * 4160 + r * 65 + c];
        b[0] = rg[j].x; b[1] = rg[j].y; b[2] = rg[j].z; b[3] = rg[j].w;
      }
    };
    for (int i = tid; i < NPTS; i += 256) z[i] = kappaf[i];
    loadDI(0);
    int cur = 0;
    float ldacc = 0.f;
    for (int p = 0; p < 16; ++p){
      for (int rb = p; rb < 16; ++rb){
        store(cur);
        int np = p, nr2 = rb + 1;
        if (nr2 >= 16){ np = p + 1; nr2 = np; }
        if (np < 16){ if (nr2 == np) loadDI(np); else loadL(nr2, np); }
        __syncthreads();
        if (rb == p && tid < 64) ldacc += logf(bufp[cur * 4160 + tid * 65 + tid]);
        int rr = tid & 63, q = tid >> 6;
        float s = 0.f;
#pragma unroll
        for (int cc = 0; cc < 16; ++cc)
          s += bufp[cur * 4160 + rr * 65 + q * 16 + cc] * z[p * 64 + q * 16 + cc];
        part[q * 64 + rr] = s;
        __syncthreads();
        if (tid < 64){
          float v = part[tid] + part[64 + tid] + part[128 + tid] + part[192 + tid];
          if (rb == p) z[p * 64 + tid] = v;
          else z[rb * 64 + tid] -= v;
        }
        __syncthreads();
        cur ^= 1;
      }
    }
    float q2 = 0.f;
    for (int i = tid; i < NPTS; i += 256) q2 += z[i] * z[i];
    int wid = tid >> 6, lane = tid & 63;
    for (int o = 32; o; o >>= 1) q2 += __shfl_down(q2, o);
    if (lane == 0) redq[wid] = q2;
    __syncthreads();
    if (tid < 64){
      float ldv = ldacc;
      for (int o = 32; o; o >>= 1) ldv += __shfl_down(ldv, o);
      if (tid == 0){
        float q2t = redq[0] + redq[1] + redq[2] + redq[3];
        mll[d] = 0.5f * q2t + ldv - 0.5f * ldetK[0] - 709.7827128933839f;
      }
    }
    __syncthreads();
  }
}

// ---- the cooperative per-step kernel ----
__global__ void __launch_bounds__(256) k_gibbs_coop(
    float* bufA, float* dinvF, const float* Kinvp, float* omega,
    const float* kappaf, float* epsb, float* fbuf,
    const float* ldetK, float* mll, int c0, int nb, int mode,
    u32 k1a, u32 k1b, u32 k2a, u32 k2b)
{
  cg::grid_group grid = cg::this_grid();
  __shared__ __align__(16) float smem[10880];
  int tid = threadIdx.x;
  float* shA = smem;
  float* shB = smem + 4352;
  float* dgl = smem + 8704;
  if (mode == 0){
    ph_geneps(k1a, k1b, epsb, c0, nb, tid);
    grid.sync();
  }
  ph_buildA(Kinvp, omega, bufA, c0, nb, mode, tid);
  grid.sync();
  ph_diag0(bufA, dinvF, nb, tid, shA, shB, dgl);
  grid.sync();
  for (int p = 0; p < 15; ++p){
    ph_panel(bufA, dinvF, p, nb, tid, shA, shB);
    grid.sync();
    ph_update(bufA, dinvF, p, nb, tid, shA, shB, dgl);
    grid.sync();
  }
  if (mode == 0){
    ph_solve(bufA, dinvF, kappaf, epsb, fbuf, c0, nb, tid, smem);
    grid.sync();
    ph_pg(k2a, k2b, fbuf, omega, c0, nb, tid);
  } else {
    ph_final(bufA, dinvF, kappaf, ldetK, mll, c0, nb, tid, smem);
  }
}

// ---------------- init + misc standalone kernels ----------------
__global__ __launch_bounds__(256) void k_gen_eps(u32 ka, u32 kb, float* eps){
  int i = blockIdx.x * 256 + threadIdx.x;
  if (i >= NDRAWS * NPTS) return;
  u32 bits = rand32(ka, kb, (u32)i, (u32)(NDRAWS * NPTS));
  eps[i] = normal_from_bits(bits);
}

__global__ __launch_bounds__(256) void k_init_f2(const float* Lf, const float* eps, float* f){
  int d = blockIdx.y, rb = blockIdx.x;
  __shared__ float tile[64][65];
  __shared__ float ev[64];
  __shared__ float part[4][64];
  int tid = threadIdx.x;
  int r = tid & 63, q = tid >> 6;
  float acc = 0.f;
  for (int kt = 0; kt <= rb; ++kt){
    __syncthreads();
#pragma unroll
    for (int j = 0; j < 4; ++j){
      int e = j * 1024 + tid * 4; int rr = e >> 6, cc = e & 63;
      float4 v = *(const float4*)&Lf[(size_t)(rb * 64 + rr) * NPTS + kt * 64 + cc];
      tile[rr][cc] = v.x; tile[rr][cc + 1] = v.y; tile[rr][cc + 2] = v.z; tile[rr][cc + 3] = v.w;
    }
    if (tid < 64) ev[tid] = eps[(size_t)d * NPTS + kt * 64 + tid];
    __syncthreads();
    int cmax = (kt == rb) ? (r + 1) : 64;
    for (int cc = q * 16; cc < q * 16 + 16; ++cc){
      if (cc < cmax) acc += tile[r][cc] * ev[cc];
    }
  }
  part[q][r] = acc;
  __syncthreads();
  if (tid < 64){
    float s = part[0][tid] + part[1][tid] + part[2][tid] + part[3][tid];
    f[(size_t)d * NPTS + rb * 64 + tid] = s;
  }
}

__global__ __launch_bounds__(256) void k_pg(u32 ka, u32 kb, const float* f, float* omega){
  int idx = blockIdx.x * 256 + threadIdx.x;
  if (idx >= NDRAWS * NPTS) return;
  float c = f[idx];
  float c2w = (c * c) / 39.47841760435743f;
  float sum = 0.f;
  u32 base = (u32)idx * NG;
  for (int g = 0; g < NG; ++g){
    u32 bits = rand32(ka, kb, base + (u32)g, (u32)(NDRAWS * NPTS * NG));
    float u = u01f(bits);
    float e = -log1pf(-u);
    float kk = (float)g + 0.5f;
    sum += e / (kk * kk + c2w);
  }
  omega[idx] = sum / 19.739208802178716f;
}

__global__ void k_out(const float* mll, float* out){
  if (threadIdx.x == 0){
    float s = 0.f;
    for (int dd = 0; dd < NDRAWS; ++dd) s += mll[dd];
    float m = s / (float)NDRAWS;
    out[0] = (-m) / (float)NPTS;
  }
}

// ---------------- host-side key derivation ----------------
static void host_split(u32 ka, u32 kb, int num, u32* outA, u32* outB){
#if PARTITIONABLE
  for (int j = 0; j < num; ++j) tf2x32(ka, kb, 0u, (u32)j, &outA[j], &outB[j]);
#else
  u32 flat[40];
  for (int k = 0; k < num; ++k){
    u32 a, b; tf2x32(ka, kb, (u32)k, (u32)(num + k), &a, &b);
    flat[k] = a; flat[num + k] = b;
  }
  for (int j = 0; j < num; ++j){ outA[j] = flat[2 * j]; outB[j] = flat[2 * j + 1]; }
#endif
}

extern "C" void kernel_launch(void* const* d_in, const int* in_sizes, int n_in,
                              void* d_out, int out_size, void* d_ws, size_t ws_size,
                              hipStream_t stream){
  const float* X  = (const float*)d_in[0];
  const int*   Y  = (const int*)d_in[1];
  const float* osp = (const float*)d_in[2];
  const float* lsp = (const float*)d_in[3];
  float* out = (float*)d_out;

  const size_t NN = (size_t)NPTS * NPTS;
  char* p = (char*)d_ws;
  // ---- persistent region ----
  float* Kinvp  = (float*)p;  p += AST * 4;
  float* omega  = (float*)p;  p += (size_t)NDRAWS * NPTS * 4;
  float* fbuf   = (float*)p;  p += (size_t)NDRAWS * NPTS * 4;
  float* epsb   = (float*)p;  p += (size_t)NDRAWS * NPTS * 4;
  float* kappaf = (float*)p;  p += NPTS * 4;
  float* x2     = (float*)p;  p += NPTS * 4;
  float* mll    = (float*)p;  p += 128;
  float* ldetK  = (float*)p;  p += 128;
  uintptr_t ip = (uintptr_t)p; ip = (ip + 255) & ~(uintptr_t)255;
  char* cb = (char*)ip;

  // ---- setup-only aliases ----
  double* Ld    = (double*)cb;                                        // 8 MB
  double* Td    = (double*)(cb + NN * 8);                             // 8 MB
  double* DinvD = (double*)(cb + NN * 16);                            // 512 KB
  float*  Lf    = (float*)(cb + NN * 16 + (size_t)16 * 4096 * 8);     // 4 MB
  double* Gslc  = (double*)(cb + NN * 16 + (size_t)16 * 4096 * 8 + NN * 4);  // 7.9 MB

  // ---- chunk buffers (overlay same region) ----
  size_t rem = ws_size - (size_t)(cb - (char*)d_ws);
  const size_t PER_DRAW = AST * 4 + (size_t)16 * 4096 * 4;
  int CH = (int)(rem / PER_DRAW);
  if (CH > NDRAWS) CH = NDRAWS;
  if (CH < 1) CH = 1;
  float* bufA  = (float*)cb;
  float* dinvF = (float*)(cb + (size_t)CH * AST * 4);

  // ---- keys ----
  u32 r3A[3], r3B[3];
  host_split(0u, 42u, 3, r3A, r3B);
  u32 kiA = r3A[0], kiB = r3B[0];
  u32 koA = r3A[1], koB = r3B[1];
  u32 klA = r3A[2], klB = r3B[2];
  u32 kkA[NSTEPS], kkB[NSTEPS];
  host_split(klA, klB, NSTEPS, kkA, kkB);
  u32 k1A[NSTEPS], k1B[NSTEPS], k2A[NSTEPS], k2B[NSTEPS];
  for (int t = 0; t < NSTEPS; ++t){
    u32 sA[2], sB[2];
    host_split(kkA[t], kkB[t], 2, sA, sB);
    k1A[t] = sA[0]; k1B[t] = sB[0];
    k2A[t] = sA[1]; k2B[t] = sB[1];
  }

  // ---- cooperative grid size ----
  int maxb = 0;
  if (hipOccupancyMaxActiveBlocksPerMultiprocessor(&maxb, k_gibbs_coop, 256, 0) != hipSuccess || maxb < 1)
    maxb = 2;
  if (maxb > 3) maxb = 3;
  int G = maxb * 256;   // 256 CUs on MI355X

  // ---- setup: K (f64), chol, Lf, logdet, slice-parallel trinv, packed flipped Kinv ----
  k_prep<<<dim3(4), 256, 0, stream>>>(X, Y, x2, kappaf);
  k_computeK<<<dim3(64, 64), dim3(16, 16), 0, stream>>>(X, x2, osp, lsp, Ld);
  run_chol_d(Ld, DinvD, stream);
  k_castL<<<dim3(4096), 256, 0, stream>>>(Ld, Lf);
  k_logdetK<<<dim3(1), 256, 0, stream>>>(Ld, ldetK);
  k_trinv_copy_diag<<<dim3(16), 256, 0, stream>>>(DinvD, Td);
  for (int lev = 1; lev < 16; ++lev){
    k_trinv_part<<<dim3(16 - lev, lev), 256, 0, stream>>>(Ld, Td, Gslc, lev);
    k_trinv_fin<<<dim3(16 - lev), 256, 0, stream>>>(Td, Gslc, lev);
  }
  k_syrk_kinv_flip<<<dim3(NTRI), 256, 0, stream>>>(Td, Kinvp);

  // ---- initial Gibbs state ----
  k_gen_eps<<<dim3(80), 256, 0, stream>>>(kiA, kiB, epsb);
  k_init_f2<<<dim3(16, NDRAWS), 256, 0, stream>>>(Lf, epsb, fbuf);
  k_pg<<<dim3(80), 256, 0, stream>>>(koA, koB, fbuf, omega);

  // ---- Gibbs steps: one cooperative launch per (step, chunk) ----
  int c0v, nbv, modev;
  u32 a1, b1, a2, b2;
  void* cargs[16] = {&bufA, &dinvF, &Kinvp, &omega, &kappaf, &epsb, &fbuf,
                     &ldetK, &mll, &c0v, &nbv, &modev, &a1, &b1, &a2, &b2};
  for (int t = 0; t < NSTEPS; ++t){
    for (int c0 = 0; c0 < NDRAWS; c0 += CH){
      c0v = c0;
      nbv = (NDRAWS - c0 < CH) ? (NDRAWS - c0) : CH;
      modev = 0;
      a1 = k1A[t]; b1 = k1B[t]; a2 = k2A[t]; b2 = k2B[t];
      hipLaunchCooperativeKernel((const void*)k_gibbs_coop, dim3(G), dim3(256), cargs, 0, stream);
    }
  }

  // ---- final mll (Woodbury) ----
  for (int c0 = 0; c0 < NDRAWS; c0 += CH){
    c0v = c0;
    nbv = (NDRAWS - c0 < CH) ? (NDRAWS - c0) : CH;
    modev = 1;
    a1 = 0; b1 = 0; a2 = 0; b2 = 0;
    hipLaunchCooperativeKernel((const void*)k_gibbs_coop, dim3(G), dim3(256), cargs, 0, stream);
  }
  k_out<<<dim3(1), 64, 0, stream>>>(mll, out);
}

// Round 9
// 26471.692 us; speedup vs baseline: 1.5639x; 1.5639x over previous
//
#include <hip/hip_runtime.h>
#include <stdint.h>

#define NPTS 1024
#define NDRAWS 20
#define NSTEPS 10
#define NG 100
#define PARTITIONABLE 1

#define TRI(i) (((i) * ((i) + 1)) / 2)
#define NTRI 136                      // 16*17/2
#define AST ((size_t)NTRI * 4096)     // floats per packed lower-tri matrix

typedef unsigned int u32;

// ---------------- threefry2x32 (JAX-compatible, 20 rounds) ----------------
__host__ __device__ static inline void tf2x32(u32 k0, u32 k1, u32 x0, u32 x1, u32* o0, u32* o1){
  u32 ks2 = k0 ^ k1 ^ 0x1BD11BDAu;
  x0 += k0; x1 += k1;
#define TFR(r) { x0 += x1; x1 = (x1 << r) | (x1 >> (32 - r)); x1 ^= x0; }
  TFR(13) TFR(15) TFR(26) TFR(6)
  x0 += k1; x1 += ks2 + 1u;
  TFR(17) TFR(29) TFR(16) TFR(24)
  x0 += ks2; x1 += k0 + 2u;
  TFR(13) TFR(15) TFR(26) TFR(6)
  x0 += k0; x1 += k1 + 3u;
  TFR(17) TFR(29) TFR(16) TFR(24)
  x0 += k1; x1 += ks2 + 4u;
  TFR(13) TFR(15) TFR(26) TFR(6)
  x0 += ks2; x1 += k0 + 5u;
#undef TFR
  *o0 = x0; *o1 = x1;
}

__device__ static inline u32 rand32(u32 ka, u32 kb, u32 i, u32 total){
  u32 a, b;
#if PARTITIONABLE
  (void)total;
  tf2x32(ka, kb, 0u, i, &a, &b);
  return a ^ b;
#else
  u32 h = total >> 1;
  if (i < h){ tf2x32(ka, kb, i, i + h, &a, &b); return a; }
  else      { tf2x32(ka, kb, i - h, i, &a, &b); return b; }
#endif
}

__device__ static inline float u01f(u32 bits){
  return __uint_as_float(0x3F800000u | (bits >> 9)) - 1.0f;
}

// XLA ErfInv32 (Giles) polynomial
__device__ static inline float erfinv32(float x){
  float w = -log1pf(-x * x);
  float p;
  if (w < 5.0f){
    w -= 2.5f;
    p = 2.81022636e-08f;
    p = fmaf(p, w, 3.43273939e-07f);
    p = fmaf(p, w, -3.5233877e-06f);
    p = fmaf(p, w, -4.39150654e-06f);
    p = fmaf(p, w, 0.00021858087f);
    p = fmaf(p, w, -0.00125372503f);
    p = fmaf(p, w, -0.00417768164f);
    p = fmaf(p, w, 0.246640727f);
    p = fmaf(p, w, 1.50140941f);
  } else {
    w = sqrtf(w) - 3.0f;
    p = -0.000200214257f;
    p = fmaf(p, w, 0.000100950558f);
    p = fmaf(p, w, 0.00134934322f);
    p = fmaf(p, w, -0.00367342844f);
    p = fmaf(p, w, 0.00573950773f);
    p = fmaf(p, w, -0.0076224613f);
    p = fmaf(p, w, 0.00943887047f);
    p = fmaf(p, w, 1.00167406f);
    p = fmaf(p, w, 2.83297682f);
  }
  return p * x;
}

__device__ static inline float normal_from_bits(u32 bits){
  const float LO = -0.99999994f;
  float u = u01f(bits);
  float v = u * 2.0f + LO;
  v = fmaxf(LO, v);
  return 1.4142135623730951f * erfinv32(v);
}

__device__ inline float  tsqrt(float x){ return sqrtf(x); }
__device__ inline double tsqrt(double x){ return sqrt(x); }
__device__ inline float  tmax(float a, float b){ return fmaxf(a, b); }
__device__ inline double tmax(double a, double b){ return fmax(a, b); }

__device__ inline void tri_decode(int p, int& ti, int& tj){
  int t = (int)((sqrtf(8.0f * (float)p + 1.0f) - 1.0f) * 0.5f);
  while ((t + 1) * (t + 2) / 2 <= p) ++t;
  while (t * (t + 1) / 2 > p) --t;
  ti = t; tj = p - t * (t + 1) / 2;
}

// interleaved right-looking chol + trinv of a 64x64 tile in LDS (256 threads)
template<typename T, int S>
__device__ inline void chol_inv_64t(T* t, T* Xs, T* diagL, int tid){
  for (int idx = tid; idx < 4096; idx += 256){
    int r = idx >> 6, c = idx & 63;
    Xs[r * S + c] = (r == c) ? (T)1 : (T)0;
  }
  __syncthreads();
  for (int j = 0; j < 64; ++j){
    T piv = tsqrt(tmax(t[j * S + j], (T)1e-30));
    T inv = (T)1 / piv;
    if (tid < 64){
      int r = j + 1 + tid;
      if (r < 64) t[r * S + j] *= inv;
      if (tid == 0) diagL[j] = piv;
    } else if (tid < 128){
      Xs[j * S + (tid - 64)] *= inv;
    }
    __syncthreads();
    int tg = tid >> 6, tr = tid & 63;
    for (int r2 = j + 1 + tg; r2 < 64; r2 += 4){
      T lj = t[r2 * S + j];
      int c = j + 1 + tr;
      if (c <= r2) t[r2 * S + c] -= lj * t[c * S + j];
      Xs[r2 * S + tr] = Xs[r2 * S + tr] - lj * Xs[j * S + tr];
    }
    __syncthreads();
  }
  if (tid < 64) t[tid * S + tid] = diagL[tid];
  __syncthreads();
}

// ---------------- setup kernels ----------------
__global__ __launch_bounds__(256) void k_prep(const float* X, const int* Y, float* x2, float* kappaf){
  int n = blockIdx.x * 256 + threadIdx.x;
  if (n >= NPTS) return;
  float s = 0.f;
  for (int d = 0; d < 64; ++d){ float v = X[n * 64 + d]; s += v * v; }
  x2[n] = s;
  kappaf[NPTS - 1 - n] = (float)Y[n] - 0.5f;
}

__global__ void k_computeK(const float* X, const float* x2, const float* osp, const float* lsp,
                           double* Ld){
  int j = blockIdx.x * 16 + threadIdx.x;
  int i = blockIdx.y * 16 + threadIdx.y;
  float os = osp[0], ls = lsp[0];
  float dot = 0.f;
  for (int d = 0; d < 64; ++d) dot += X[i * 64 + d] * X[j * 64 + d];
  float d2 = x2[i] + x2[j] - 2.0f * dot;
  d2 = fmaxf(d2, 0.0f);
  float kv = os * expf((-0.5f * d2) / (ls * ls));
  Ld[(size_t)i * NPTS + j] = (double)kv + (i == j ? 1e-6 : 0.0);
}

__global__ __launch_bounds__(256) void k_castL(const double* Ld, float* Lf){
  int idx = blockIdx.x * 256 + threadIdx.x;
  int i = idx >> 10, j = idx & 1023;
  Lf[idx] = (j <= i) ? (float)Ld[idx] : 0.0f;
}

__global__ __launch_bounds__(256) void k_logdetK(const double* Ld, float* ldetK){
  __shared__ double red[4];
  int tid = threadIdx.x;
  double s = 0.0;
  for (int i = tid; i < NPTS; i += 256) s += log(Ld[(size_t)i * NPTS + i]);
  for (int o = 32; o; o >>= 1) s += __shfl_down(s, o);
  if ((tid & 63) == 0) red[tid >> 6] = s;
  __syncthreads();
  if (tid == 0) ldetK[0] = (float)(2.0 * (red[0] + red[1] + red[2] + red[3]));
}

// ---------------- f64 dense blocked Cholesky (setup only) ----------------
__global__ __launch_bounds__(256) void k_chol_diag_inv_d(double* M, double* Dinv, int p){
  double* DI = Dinv + (size_t)p * 4096;
  int k0 = p * 64;
  __shared__ double t[64][65];
  __shared__ double Xs[64][65];
  __shared__ double diagL[64];
  int tid = threadIdx.x;
  for (int idx = tid; idx < 4096; idx += 256){
    int r = idx >> 6, c = idx & 63;
    t[r][c] = (c <= r) ? M[(size_t)(k0 + r) * NPTS + k0 + c] : 0.0;
  }
  __syncthreads();
  chol_inv_64t<double, 65>(&t[0][0], &Xs[0][0], &diagL[0], tid);
  for (int idx = tid; idx < 4096; idx += 256){
    int r = idx >> 6, c = idx & 63;
    M[(size_t)(k0 + r) * NPTS + k0 + c] = (c <= r) ? t[r][c] : 0.0;
    DI[idx] = Xs[r][c];
  }
}

__global__ __launch_bounds__(256) void k_chol_panel_d(double* M, const double* Dinv, int p){
  const double* DI = Dinv + (size_t)p * 4096;
  int r0 = (p + 1) * 64 + blockIdx.x * 64;
  __shared__ double Rs[64][65];
  __shared__ double Ds[64][65];
  int tid = threadIdx.x;
  for (int idx = tid; idx < 4096; idx += 256){
    int r = idx >> 6, c = idx & 63;
    Rs[r][c] = M[(size_t)(r0 + r) * NPTS + p * 64 + c];
    Ds[r][c] = DI[idx];
  }
  __syncthreads();
  int tx = tid & 15, ty = tid >> 4;
  double acc[4][4];
#pragma unroll
  for (int a = 0; a < 4; ++a)
#pragma unroll
    for (int b = 0; b < 4; ++b) acc[a][b] = 0.0;
  for (int k = 0; k < 64; ++k){
    double av[4], bv[4];
#pragma unroll
    for (int a = 0; a < 4; ++a) av[a] = Rs[ty * 4 + a][k];
#pragma unroll
    for (int b = 0; b < 4; ++b) bv[b] = Ds[tx * 4 + b][k];
#pragma unroll
    for (int a = 0; a < 4; ++a)
#pragma unroll
      for (int b = 0; b < 4; ++b) acc[a][b] += av[a] * bv[b];
  }
#pragma unroll
  for (int a = 0; a < 4; ++a)
#pragma unroll
    for (int b = 0; b < 4; ++b)
      M[(size_t)(r0 + ty * 4 + a) * NPTS + p * 64 + tx * 4 + b] = acc[a][b];
}

__global__ __launch_bounds__(256) void k_chol_update_d(double* M, int k0){
  __shared__ double Pa[64][65];
  __shared__ double Pb[64][65];
  int ti, tj; tri_decode(blockIdx.x, ti, tj);
  int bi = k0 + 64 + ti * 64;
  int bj = k0 + 64 + tj * 64;
  int tid = threadIdx.x;
  for (int idx = tid; idx < 4096; idx += 256){
    int r = idx >> 6, c = idx & 63;
    Pa[r][c] = M[(size_t)(bi + r) * NPTS + k0 + c];
    Pb[r][c] = M[(size_t)(bj + r) * NPTS + k0 + c];
  }
  __syncthreads();
  int tx = tid & 15, ty = tid >> 4;
  double acc[4][4];
#pragma unroll
  for (int a = 0; a < 4; ++a)
#pragma unroll
    for (int b = 0; b < 4; ++b) acc[a][b] = 0.0;
  for (int k = 0; k < 64; ++k){
    double av[4], bv[4];
#pragma unroll
    for (int a = 0; a < 4; ++a) av[a] = Pa[ty * 4 + a][k];
#pragma unroll
    for (int b = 0; b < 4; ++b) bv[b] = Pb[tx * 4 + b][k];
#pragma unroll
    for (int a = 0; a < 4; ++a)
#pragma unroll
      for (int b = 0; b < 4; ++b) acc[a][b] += av[a] * bv[b];
  }
#pragma unroll
  for (int a = 0; a < 4; ++a)
#pragma unroll
    for (int b = 0; b < 4; ++b){
      int gi = bi + ty * 4 + a, gj = bj + tx * 4 + b;
      M[(size_t)gi * NPTS + gj] -= acc[a][b];
    }
}

static void run_chol_d(double* A, double* Dinv, hipStream_t s){
  for (int p = 0; p < 16; ++p){
    k_chol_diag_inv_d<<<dim3(1), 256, 0, s>>>(A, Dinv, p);
    int nrb = 15 - p;
    if (nrb > 0){
      k_chol_panel_d<<<dim3(nrb), 256, 0, s>>>(A, Dinv, p);
      k_chol_update_d<<<dim3(nrb * (nrb + 1) / 2), 256, 0, s>>>(A, p * 64);
    }
  }
}

// ---------------- f64 triangular inverse (one-time, for Kinv), slice-parallel ----------------
__global__ __launch_bounds__(256) void k_trinv_copy_diag(const double* DinvD, double* Td){
  int p = blockIdx.x;
  for (int idx = threadIdx.x; idx < 4096; idx += 256){
    int r = idx >> 6, c = idx & 63;
    Td[(size_t)(p * 64 + r) * NPTS + p * 64 + c] = DinvD[(size_t)p * 4096 + idx];
  }
}

__global__ __launch_bounds__(256) void k_trinv_part(const double* Lm, const double* Td,
                                                    double* Gs, int lev){
  int J = blockIdx.x, s = blockIdx.y;
  int I = J + lev, K = J + s;
  __shared__ double Ta[64][65];
  __shared__ double Tb[64][65];
  int tid = threadIdx.x, tx = tid & 15, ty = tid >> 4;
  for (int idx = tid; idx < 4096; idx += 256){
    int r = idx >> 6, c = idx & 63;
    Ta[r][c] = Lm[(size_t)(I * 64 + r) * NPTS + K * 64 + c];
    Tb[r][c] = Td[(size_t)(K * 64 + r) * NPTS + J * 64 + c];
  }
  __syncthreads();
  double acc[4][4];
#pragma unroll
  for (int a = 0; a < 4; ++a)
#pragma unroll
    for (int b = 0; b < 4; ++b) acc[a][b] = 0.0;
  for (int k = 0; k < 64; ++k){
    double av[4], bv[4];
#pragma unroll
    for (int a = 0; a < 4; ++a) av[a] = Ta[ty * 4 + a][k];
#pragma unroll
    for (int b = 0; b < 4; ++b) bv[b] = Tb[k][tx * 4 + b];
#pragma unroll
    for (int a = 0; a < 4; ++a)
#pragma unroll
      for (int b = 0; b < 4; ++b) acc[a][b] += av[a] * bv[b];
  }
  double* out = Gs + ((size_t)J * 15 + s) * 4096;
#pragma unroll
  for (int a = 0; a < 4; ++a)
#pragma unroll
    for (int b = 0; b < 4; ++b)
      out[(ty * 4 + a) * 64 + tx * 4 + b] = acc[a][b];
}

__global__ __launch_bounds__(256) void k_trinv_fin(double* Td, const double* Gs, int lev){
  int J = blockIdx.x, I = J + lev;
  __shared__ double Ta[64][65];
  __shared__ double Tb[64][65];
  int tid = threadIdx.x, tx = tid & 15, ty = tid >> 4;
  for (int idx = tid; idx < 4096; idx += 256){
    int r = idx >> 6, c = idx & 63;
    double g = 0.0;
    for (int s = 0; s < lev; ++s) g += Gs[((size_t)J * 15 + s) * 4096 + idx];
    Tb[r][c] = g;
    Ta[r][c] = Td[(size_t)(I * 64 + r) * NPTS + I * 64 + c];
  }
  __syncthreads();
  double ac2[4][4];
#pragma unroll
  for (int a = 0; a < 4; ++a)
#pragma unroll
    for (int b = 0; b < 4; ++b) ac2[a][b] = 0.0;
  for (int k = 0; k < 64; ++k){
    double av[4], bv[4];
#pragma unroll
    for (int a = 0; a < 4; ++a) av[a] = Ta[ty * 4 + a][k];
#pragma unroll
    for (int b = 0; b < 4; ++b) bv[b] = Tb[k][tx * 4 + b];
#pragma unroll
    for (int a = 0; a < 4; ++a)
#pragma unroll
      for (int b = 0; b < 4; ++b) ac2[a][b] += av[a] * bv[b];
  }
#pragma unroll
  for (int a = 0; a < 4; ++a)
#pragma unroll
    for (int b = 0; b < 4; ++b)
      Td[(size_t)(I * 64 + ty * 4 + a) * NPTS + J * 64 + tx * 4 + b] = -ac2[a][b];
}

__global__ __launch_bounds__(256) void k_syrk_kinv_flip(const double* Td, float* Kinvp){
  int a0, b0; tri_decode(blockIdx.x, a0, b0);   // a0 >= b0
  int ti = b0, tj = a0;                          // ti <= tj
  int kmin = tj;
  __shared__ double Ta[64][65];
  __shared__ double Tb[64][65];
  int tid = threadIdx.x, tx = tid & 15, ty = tid >> 4;
  double acc[4][4];
#pragma unroll
  for (int a = 0; a < 4; ++a)
#pragma unroll
    for (int b = 0; b < 4; ++b) acc[a][b] = 0.0;
  for (int K = kmin; K < 16; ++K){
    __syncthreads();
    for (int idx = tid; idx < 4096; idx += 256){
      int r = idx >> 6, c = idx & 63;
      Ta[r][c] = Td[(size_t)(K * 64 + r) * NPTS + ti * 64 + c];
      Tb[r][c] = Td[(size_t)(K * 64 + r) * NPTS + tj * 64 + c];
    }
    __syncthreads();
    for (int k = 0; k < 64; ++k){
      double av[4], bv[4];
#pragma unroll
      for (int a = 0; a < 4; ++a) av[a] = Ta[k][ty * 4 + a];
#pragma unroll
      for (int b = 0; b < 4; ++b) bv[b] = Tb[k][tx * 4 + b];
#pragma unroll
      for (int a = 0; a < 4; ++a)
#pragma unroll
        for (int b = 0; b < 4; ++b) acc[a][b] += av[a] * bv[b];
    }
  }
  int tileR = 15 - ti, tileC = 15 - tj;
  float* out = Kinvp + (size_t)(TRI(tileR) + tileC) * 4096;
#pragma unroll
  for (int a = 0; a < 4; ++a)
#pragma unroll
    for (int b = 0; b < 4; ++b){
      int rin = 63 - (ty * 4 + a), cin = 63 - (tx * 4 + b);
      out[rin * 64 + cin] = (float)acc[a][b];
    }
}

// ================= fused per-step kernels (S-matrix scheme) =================
// Invariant: A tiles are NEVER overwritten with L. Tile (r,k) holds Ahat(r,k)
// (A updated through stage k-1). L(r,k) = Ahat(r,k)*DI(k)^T implicitly.
// S(k) = DI(k)^T * DI(k).

// stage0: buildA (all tiles) + diag0 chol/inv/S + (optional) eps generation
__global__ __launch_bounds__(256) void k_stage0(const float* Kinvp, const float* omega,
    float* Ab, float* DinvF, float* Sbuf, float* epsb,
    int c0, int nb, int clip, int doeps, u32 ka, u32 kb){
  int nA = 544 * nb;
  int task = blockIdx.x, tid = threadIdx.x;
  if (task < nA){
    int dd = task / 544, blk = task - dd * 544;
    int d = c0 + dd;
    float* A = Ab + (size_t)dd * AST;
    int idx4 = blk * 256 + tid;
    float4 v = ((const float4*)Kinvp)[idx4];
    int tile = idx4 >> 10;
    int ti, tj; tri_decode(tile, ti, tj);
    if (ti == tj){
      int e = (idx4 & 1023) * 4;
      int r = e >> 6, c = e & 63;
      if (c <= r && r < c + 4){
        float om = omega[(size_t)d * NPTS + (NPTS - 1 - (ti * 64 + r))];
        if (clip) om = fmaxf(om, 1e-16f);
        ((float*)&v)[r - c] += om;
      }
    }
    ((float4*)A)[idx4] = v;
  } else if (task < nA + nb){
    int dd = task - nA, d = c0 + dd;
    __shared__ float t[64 * 65];
    __shared__ float Xs[64 * 65];
    __shared__ float diagL[64];
    for (int idx = tid; idx < 1024; idx += 256){
      float4 v = ((const float4*)Kinvp)[idx];           // tile (0,0) is first
      int e = idx * 4, r = e >> 6, c = e & 63;
      t[r * 65 + c] = v.x; t[r * 65 + c + 1] = v.y;
      t[r * 65 + c + 2] = v.z; t[r * 65 + c + 3] = v.w;
    }
    __syncthreads();
    if (tid < 64){
      float om = omega[(size_t)d * NPTS + (NPTS - 1 - tid)];
      if (clip) om = fmaxf(om, 1e-16f);
      t[tid * 65 + tid] += om;
    }
    __syncthreads();
    chol_inv_64t<float, 65>(t, Xs, diagL, tid);
    float* DI = DinvF + (size_t)dd * 16 * 4096;
    for (int idx = tid; idx < 1024; idx += 256){
      int e = idx * 4, r = e >> 6, c = e & 63;
      float4 w;
      w.x = Xs[r * 65 + c]; w.y = Xs[r * 65 + c + 1];
      w.z = Xs[r * 65 + c + 2]; w.w = Xs[r * 65 + c + 3];
      ((float4*)DI)[idx] = w;
    }
    // S(0) = DI^T * DI
    int tx = tid & 15, ty = tid >> 4;
    float sa[4][4];
#pragma unroll
    for (int a = 0; a < 4; ++a)
#pragma unroll
      for (int b = 0; b < 4; ++b) sa[a][b] = 0.f;
    for (int m = 0; m < 64; ++m){
      float av[4], bv[4];
#pragma unroll
      for (int a = 0; a < 4; ++a) av[a] = Xs[m * 65 + ty * 4 + a];
#pragma unroll
      for (int b = 0; b < 4; ++b) bv[b] = Xs[m * 65 + tx * 4 + b];
#pragma unroll
      for (int a = 0; a < 4; ++a)
#pragma unroll
        for (int b = 0; b < 4; ++b) sa[a][b] += av[a] * bv[b];
    }
    float* So = Sbuf + (size_t)dd * 16 * 4096;
#pragma unroll
    for (int a = 0; a < 4; ++a)
#pragma unroll
      for (int b = 0; b < 4; ++b)
        So[(ty * 4 + a) * 64 + tx * 4 + b] = sa[a][b];
  } else if (doeps){
    int i = (task - nA - nb) * 256 + tid;
    if (i < nb * NPTS){
      int g = c0 * NPTS + i;
      u32 bits = rand32(ka, kb, (u32)g, (u32)(NDRAWS * NPTS));
      epsb[g] = normal_from_bits(bits);
    }
  }
}

// fused update stage p: A(bi,bj) -= A(bi,p)*S(p)*A(bj,p)^T for all trailing pairs;
// the (p+1,p+1) block additionally chols+inverts its tile, emits DI(p+1), S(p+1).
__global__ __launch_bounds__(256) void k_updstage(float* Ab, float* DinvF, float* Sbuf,
                                                  int p, int npairs){
  int task = blockIdx.x, tid = threadIdx.x;
  int dd = task / npairs, pr = task - dd * npairs;
  int t0, t1; tri_decode(pr, t0, t1);        // t0 >= t1
  int bi = p + 1 + t0, bj = p + 1 + t1;
  float* M = Ab + (size_t)dd * AST;
  const float* Sp = Sbuf + ((size_t)dd * 16 + p) * 4096;
  __shared__ float A1[64 * 65];
  __shared__ float A2[64 * 65];
  __shared__ float Xb[64 * 65];
  __shared__ float diagL[64];
  int tx = tid & 15, ty = tid >> 4;
  const float* Abi = M + (size_t)(TRI(bi) + p) * 4096;
  for (int idx = tid; idx < 1024; idx += 256){
    float4 v = ((const float4*)Abi)[idx];
    float4 w = ((const float4*)Sp)[idx];
    int e = idx * 4, r = e >> 6, c = e & 63;
    A1[r * 65 + c] = v.x; A1[r * 65 + c + 1] = v.y;
    A1[r * 65 + c + 2] = v.z; A1[r * 65 + c + 3] = v.w;
    Xb[r * 65 + c] = w.x; Xb[r * 65 + c + 1] = w.y;
    Xb[r * 65 + c + 2] = w.z; Xb[r * 65 + c + 3] = w.w;
  }
  if (bi != bj){
    const float* Abj = M + (size_t)(TRI(bj) + p) * 4096;
    for (int idx = tid; idx < 1024; idx += 256){
      float4 v = ((const float4*)Abj)[idx];
      int e = idx * 4, r = e >> 6, c = e & 63;
      A2[r * 65 + c] = v.x; A2[r * 65 + c + 1] = v.y;
      A2[r * 65 + c + 2] = v.z; A2[r * 65 + c + 3] = v.w;
    }
  }
  __syncthreads();
  // GEMM1: T = A1 * S   (T[r][k] = sum_m A1[r][m]*S[m][k])
  float acc[4][4];
#pragma unroll
  for (int a = 0; a < 4; ++a)
#pragma unroll
    for (int b = 0; b < 4; ++b) acc[a][b] = 0.f;
  for (int m = 0; m < 64; ++m){
    float av[4], bv[4];
#pragma unroll
    for (int a = 0; a < 4; ++a) av[a] = A1[(ty * 4 + a) * 65 + m];
#pragma unroll
    for (int b = 0; b < 4; ++b) bv[b] = Xb[m * 65 + tx * 4 + b];
#pragma unroll
    for (int a = 0; a < 4; ++a)
#pragma unroll
      for (int b = 0; b < 4; ++b) acc[a][b] += av[a] * bv[b];
  }
  __syncthreads();
#pragma unroll
  for (int a = 0; a < 4; ++a)
#pragma unroll
    for (int b = 0; b < 4; ++b)
      Xb[(ty * 4 + a) * 65 + tx * 4 + b] = acc[a][b];
  __syncthreads();
  // GEMM2: acc2 = T * A2^T
  const float* A2p = (bi == bj) ? A1 : A2;
  float ac2[4][4];
#pragma unroll
  for (int a = 0; a < 4; ++a)
#pragma unroll
    for (int b = 0; b < 4; ++b) ac2[a][b] = 0.f;
  for (int k = 0; k < 64; ++k){
    float av[4], bv[4];
#pragma unroll
    for (int a = 0; a < 4; ++a) av[a] = Xb[(ty * 4 + a) * 65 + k];
#pragma unroll
    for (int b = 0; b < 4; ++b) bv[b] = A2p[(tx * 4 + b) * 65 + k];
#pragma unroll
    for (int a = 0; a < 4; ++a)
#pragma unroll
      for (int b = 0; b < 4; ++b) ac2[a][b] += av[a] * bv[b];
  }
  float* Atile = M + (size_t)(TRI(bi) + bj) * 4096;
  if (!(t0 == 0 && t1 == 0)){
#pragma unroll
    for (int a = 0; a < 4; ++a){
      float4 v = *((const float4*)&Atile[(size_t)(ty * 4 + a) * 64 + tx * 4]);
      v.x -= ac2[a][0]; v.y -= ac2[a][1]; v.z -= ac2[a][2]; v.w -= ac2[a][3];
      *((float4*)&Atile[(size_t)(ty * 4 + a) * 64 + tx * 4]) = v;
    }
  } else {
    // tile (p+1,p+1): subtract in LDS, chol+inv, emit DI(p+1), S(p+1)
    __syncthreads();
    for (int idx = tid; idx < 1024; idx += 256){
      float4 v = ((const float4*)Atile)[idx];
      int e = idx * 4, r = e >> 6, c = e & 63;
      A1[r * 65 + c] = v.x; A1[r * 65 + c + 1] = v.y;
      A1[r * 65 + c + 2] = v.z; A1[r * 65 + c + 3] = v.w;
    }
    __syncthreads();
#pragma unroll
    for (int a = 0; a < 4; ++a)
#pragma unroll
      for (int b = 0; b < 4; ++b)
        A1[(ty * 4 + a) * 65 + tx * 4 + b] -= ac2[a][b];
    __syncthreads();
    chol_inv_64t<float, 65>(A1, A2, diagL, tid);
    float* DI = DinvF + ((size_t)dd * 16 + (p + 1)) * 4096;
    for (int idx = tid; idx < 1024; idx += 256){
      int e = idx * 4, r = e >> 6, c = e & 63;
      float4 w;
      w.x = A2[r * 65 + c]; w.y = A2[r * 65 + c + 1];
      w.z = A2[r * 65 + c + 2]; w.w = A2[r * 65 + c + 3];
      ((float4*)DI)[idx] = w;
    }
    float sa[4][4];
#pragma unroll
    for (int a = 0; a < 4; ++a)
#pragma unroll
      for (int b = 0; b < 4; ++b) sa[a][b] = 0.f;
    for (int m = 0; m < 64; ++m){
      float av[4], bv[4];
#pragma unroll
      for (int a = 0; a < 4; ++a) av[a] = A2[m * 65 + ty * 4 + a];
#pragma unroll
      for (int b = 0; b < 4; ++b) bv[b] = A2[m * 65 + tx * 4 + b];
#pragma unroll
      for (int a = 0; a < 4; ++a)
#pragma unroll
        for (int b = 0; b < 4; ++b) sa[a][b] += av[a] * bv[b];
    }
    float* So = Sbuf + ((size_t)dd * 16 + (p + 1)) * 4096;
#pragma unroll
    for (int a = 0; a < 4; ++a)
#pragma unroll
      for (int b = 0; b < 4; ++b)
        So[(ty * 4 + a) * 64 + tx * 4 + b] = sa[a][b];
  }
}

// fused solve + PG draw. Uses Ahat tiles + DI (no L materialized):
//  forward: z_p = DI(p)*z_p ; y_p = DI(p)^T*z_p ; z_rb -= Ahat(rb,p)*y_p
//  backward: u_cb += Ahat(p,cb)^T*z_p ; at diag: z_p -= DI(p)*u_p ; z_p = DI(p)^T*z_p
__global__ __launch_bounds__(256) void k_solve_pg(const float* Ab, const float* DinvF,
    const float* kappaf, const float* eps, float* omega, int c0, u32 ka, u32 kb){
  int dd = blockIdx.x, d = c0 + dd;
  const float* M = Ab + (size_t)dd * AST;
  const float* DIb = DinvF + (size_t)dd * 16 * 4096;
  __shared__ float z1[1024], z2[1024], u1[1024], u2[1024], y[64];
  __shared__ float buf[2][64 * 65];
  __shared__ float p1[256], p2[256];
  int tid = threadIdx.x;
  float4 rg[4];
  auto loadDI = [&](int p){
#pragma unroll
    for (int j = 0; j < 4; ++j)
      rg[j] = *(const float4*)&DIb[p * 4096 + j * 1024 + tid * 4];
  };
  auto loadA = [&](int row, int col){
    const float* T = M + (size_t)(TRI(row) + col) * 4096;
#pragma unroll
    for (int j = 0; j < 4; ++j)
      rg[j] = *(const float4*)&T[j * 1024 + tid * 4];
  };
  auto store = [&](int cur){
#pragma unroll
    for (int j = 0; j < 4; ++j){
      int e = j * 1024 + tid * 4; int r = e >> 6, c = e & 63;
      float* b = &buf[cur][r * 65 + c];
      b[0] = rg[j].x; b[1] = rg[j].y; b[2] = rg[j].z; b[3] = rg[j].w;
    }
  };
  for (int i = tid; i < NPTS; i += 256){
    z1[i] = kappaf[i];
    z2[NPTS - 1 - i] = eps[(size_t)d * NPTS + i];
    u1[i] = 0.f; u2[i] = 0.f;
  }
  // ---- forward on z1 ----
  loadDI(0);
  int cur = 0;
  for (int p = 0; p < 16; ++p){
    for (int rb = p; rb < 16; ++rb){
      store(cur);
      int np = p, nrb = rb + 1;
      if (nrb >= 16){ np = p + 1; nrb = np; }
      if (np < 16){ if (nrb == np) loadDI(np); else loadA(nrb, np); }
      __syncthreads();
      int rr = tid & 63, q = tid >> 6;
      if (rb == p){
        float s = 0.f;
#pragma unroll
        for (int cc = 0; cc < 16; ++cc)
          s += buf[cur][rr * 65 + q * 16 + cc] * z1[p * 64 + q * 16 + cc];
        p1[q * 64 + rr] = s;
        __syncthreads();
        if (tid < 64) z1[p * 64 + tid] = p1[tid] + p1[64 + tid] + p1[128 + tid] + p1[192 + tid];
        __syncthreads();
        // y = DI^T * z1_p
        float s2 = 0.f;
#pragma unroll
        for (int r2 = 0; r2 < 16; ++r2)
          s2 += buf[cur][(q * 16 + r2) * 65 + rr] * z1[p * 64 + q * 16 + r2];
        p1[q * 64 + rr] = s2;
        __syncthreads();
        if (tid < 64) y[tid] = p1[tid] + p1[64 + tid] + p1[128 + tid] + p1[192 + tid];
        __syncthreads();
      } else {
        float s = 0.f;
#pragma unroll
        for (int cc = 0; cc < 16; ++cc)
          s += buf[cur][rr * 65 + q * 16 + cc] * y[q * 16 + cc];
        p1[q * 64 + rr] = s;
        __syncthreads();
        if (tid < 64) z1[rb * 64 + tid] -= p1[tid] + p1[64 + tid] + p1[128 + tid] + p1[192 + tid];
        __syncthreads();
      }
      cur ^= 1;
    }
  }
  // ---- backward on z1 (mu path) and z2 (noise path) ----
  loadDI(15);
  for (int p = 15; p >= 0; --p){
    for (int cb = p; cb >= 0; --cb){
      store(cur);
      int np = p, ncb = cb - 1;
      if (ncb < 0){ np = p - 1; ncb = np; }
      if (np >= 0){ if (ncb == np) loadDI(np); else loadA(np, ncb); }
      __syncthreads();
      int rr = tid & 63, q = tid >> 6;
      if (cb == p){
        // z_p -= DI * u_p (row pattern)
        float s1 = 0.f, s2 = 0.f;
#pragma unroll
        for (int cc = 0; cc < 16; ++cc){
          float t = buf[cur][rr * 65 + q * 16 + cc];
          s1 += t * u1[p * 64 + q * 16 + cc];
          s2 += t * u2[p * 64 + q * 16 + cc];
        }
        p1[q * 64 + rr] = s1; p2[q * 64 + rr] = s2;
        __syncthreads();
        if (tid < 64){
          z1[p * 64 + tid] -= p1[tid] + p1[64 + tid] + p1[128 + tid] + p1[192 + tid];
          z2[p * 64 + tid] -= p2[tid] + p2[64 + tid] + p2[128 + tid] + p2[192 + tid];
        }
        __syncthreads();
        // z_p = DI^T * z_p (col pattern)
        s1 = 0.f; s2 = 0.f;
#pragma unroll
        for (int r2 = 0; r2 < 16; ++r2){
          float t = buf[cur][(q * 16 + r2) * 65 + rr];
          s1 += t * z1[p * 64 + q * 16 + r2];
          s2 += t * z2[p * 64 + q * 16 + r2];
        }
        p1[q * 64 + rr] = s1; p2[q * 64 + rr] = s2;
        __syncthreads();
        if (tid < 64){
          z1[p * 64 + tid] = p1[tid] + p1[64 + tid] + p1[128 + tid] + p1[192 + tid];
          z2[p * 64 + tid] = p2[tid] + p2[64 + tid] + p2[128 + tid] + p2[192 + tid];
        }
        __syncthreads();
      } else {
        // u_cb += Ahat(p,cb)^T * z_p (col pattern)
        float s1 = 0.f, s2 = 0.f;
#pragma unroll
        for (int r2 = 0; r2 < 16; ++r2){
          float t = buf[cur][(q * 16 + r2) * 65 + rr];
          s1 += t * z1[p * 64 + q * 16 + r2];
          s2 += t * z2[p * 64 + q * 16 + r2];
        }
        p1[q * 64 + rr] = s1; p2[q * 64 + rr] = s2;
        __syncthreads();
        if (tid < 64){
          u1[cb * 64 + tid] += p1[tid] + p1[64 + tid] + p1[128 + tid] + p1[192 + tid];
          u2[cb * 64 + tid] += p2[tid] + p2[64 + tid] + p2[128 + tid] + p2[192 + tid];
        }
        __syncthreads();
      }
      cur ^= 1;
    }
  }
  // ---- PG draw for this draw's 1024 sites (f = P(z1+z2) in LDS) ----
  for (int i = tid; i < NPTS; i += 256){
    float c = z1[NPTS - 1 - i] + z2[NPTS - 1 - i];
    float c2w = (c * c) / 39.47841760435743f;
    float sum = 0.f;
    u32 base = (u32)((size_t)d * NPTS + i) * NG;
    for (int g = 0; g < NG; ++g){
      u32 bits = rand32(ka, kb, base + (u32)g, (u32)(NDRAWS * NPTS * NG));
      float u = u01f(bits);
      float e = -log1pf(-u);
      float kk = (float)g + 0.5f;
      sum += e / (kk * kk + c2w);
    }
    omega[(size_t)d * NPTS + i] = sum / 19.739208802178716f;
  }
}

// final (Woodbury): forward solve with kappaf; mll = 0.5||z||^2 + sum log diag(DI) - 0.5 ldetK - N log2
__global__ __launch_bounds__(256) void k_final_w(const float* Ab, const float* DinvF,
    const float* kappaf, const float* ldetK, float* mll, int c0){
  int dd = blockIdx.x, d = c0 + dd;
  const float* M = Ab + (size_t)dd * AST;
  const float* DIb = DinvF + (size_t)dd * 16 * 4096;
  __shared__ float z1[1024], y[64];
  __shared__ float buf[2][64 * 65];
  __shared__ float p1[256];
  __shared__ float redq[4];
  int tid = threadIdx.x;
  float4 rg[4];
  auto loadDI = [&](int p){
#pragma unroll
    for (int j = 0; j < 4; ++j)
      rg[j] = *(const float4*)&DIb[p * 4096 + j * 1024 + tid * 4];
  };
  auto loadA = [&](int row, int col){
    const float* T = M + (size_t)(TRI(row) + col) * 4096;
#pragma unroll
    for (int j = 0; j < 4; ++j)
      rg[j] = *(const float4*)&T[j * 1024 + tid * 4];
  };
  auto store = [&](int cur){
#pragma unroll
    for (int j = 0; j < 4; ++j){
      int e = j * 1024 + tid * 4; int r = e >> 6, c = e & 63;
      float* b = &buf[cur][r * 65 + c];
      b[0] = rg[j].x; b[1] = rg[j].y; b[2] = rg[j].z; b[3] = rg[j].w;
    }
  };
  for (int i = tid; i < NPTS; i += 256) z1[i] = kappaf[i];
  loadDI(0);
  int cur = 0;
  float ldacc = 0.f;
  for (int p = 0; p < 16; ++p){
    for (int rb = p; rb < 16; ++rb){
      store(cur);
      int np = p, nrb = rb + 1;
      if (nrb >= 16){ np = p + 1; nrb = np; }
      if (np < 16){ if (nrb == np) loadDI(np); else loadA(nrb, np); }
      __syncthreads();
      int rr = tid & 63, q = tid >> 6;
      if (rb == p){
        if (tid < 64) ldacc += logf(buf[cur][tid * 65 + tid]);
        float s = 0.f;
#pragma unroll
        for (int cc = 0; cc < 16; ++cc)
          s += buf[cur][rr * 65 + q * 16 + cc] * z1[p * 64 + q * 16 + cc];
        p1[q * 64 + rr] = s;
        __syncthreads();
        if (tid < 64) z1[p * 64 + tid] = p1[tid] + p1[64 + tid] + p1[128 + tid] + p1[192 + tid];
        __syncthreads();
        float s2 = 0.f;
#pragma unroll
        for (int r2 = 0; r2 < 16; ++r2)
          s2 += buf[cur][(q * 16 + r2) * 65 + rr] * z1[p * 64 + q * 16 + r2];
        p1[q * 64 + rr] = s2;
        __syncthreads();
        if (tid < 64) y[tid] = p1[tid] + p1[64 + tid] + p1[128 + tid] + p1[192 + tid];
        __syncthreads();
      } else {
        float s = 0.f;
#pragma unroll
        for (int cc = 0; cc < 16; ++cc)
          s += buf[cur][rr * 65 + q * 16 + cc] * y[q * 16 + cc];
        p1[q * 64 + rr] = s;
        __syncthreads();
        if (tid < 64) z1[rb * 64 + tid] -= p1[tid] + p1[64 + tid] + p1[128 + tid] + p1[192 + tid];
        __syncthreads();
      }
      cur ^= 1;
    }
  }
  float q2 = 0.f;
  for (int i = tid; i < NPTS; i += 256) q2 += z1[i] * z1[i];
  int wid = tid >> 6, lane = tid & 63;
  for (int o = 32; o; o >>= 1) q2 += __shfl_down(q2, o);
  if (lane == 0) redq[wid] = q2;
  __syncthreads();
  if (tid < 64){
    float ldv = ldacc;
    for (int o = 32; o; o >>= 1) ldv += __shfl_down(ldv, o);
    if (tid == 0){
      float q2t = redq[0] + redq[1] + redq[2] + redq[3];
      mll[d] = 0.5f * q2t + ldv - 0.5f * ldetK[0] - 709.7827128933839f;
    }
  }
}

// ---------------- init + misc standalone kernels ----------------
__global__ __launch_bounds__(256) void k_gen_eps(u32 ka, u32 kb, float* eps){
  int i = blockIdx.x * 256 + threadIdx.x;
  if (i >= NDRAWS * NPTS) return;
  u32 bits = rand32(ka, kb, (u32)i, (u32)(NDRAWS * NPTS));
  eps[i] = normal_from_bits(bits);
}

__global__ __launch_bounds__(256) void k_init_f2(const float* Lf, const float* eps, float* f){
  int d = blockIdx.y, rb = blockIdx.x;
  __shared__ float tile[64][65];
  __shared__ float ev[64];
  __shared__ float part[4][64];
  int tid = threadIdx.x;
  int r = tid & 63, q = tid >> 6;
  float acc = 0.f;
  for (int kt = 0; kt <= rb; ++kt){
    __syncthreads();
#pragma unroll
    for (int j = 0; j < 4; ++j){
      int e = j * 1024 + tid * 4; int rr = e >> 6, cc = e & 63;
      float4 v = *(const float4*)&Lf[(size_t)(rb * 64 + rr) * NPTS + kt * 64 + cc];
      tile[rr][cc] = v.x; tile[rr][cc + 1] = v.y; tile[rr][cc + 2] = v.z; tile[rr][cc + 3] = v.w;
    }
    if (tid < 64) ev[tid] = eps[(size_t)d * NPTS + kt * 64 + tid];
    __syncthreads();
    int cmax = (kt == rb) ? (r + 1) : 64;
    for (int cc = q * 16; cc < q * 16 + 16; ++cc){
      if (cc < cmax) acc += tile[r][cc] * ev[cc];
    }
  }
  part[q][r] = acc;
  __syncthreads();
  if (tid < 64){
    float s = part[0][tid] + part[1][tid] + part[2][tid] + part[3][tid];
    f[(size_t)d * NPTS + rb * 64 + tid] = s;
  }
}

__global__ __launch_bounds__(256) void k_pg(u32 ka, u32 kb, const float* f, float* omega){
  int idx = blockIdx.x * 256 + threadIdx.x;
  if (idx >= NDRAWS * NPTS) return;
  float c = f[idx];
  float c2w = (c * c) / 39.47841760435743f;
  float sum = 0.f;
  u32 base = (u32)idx * NG;
  for (int g = 0; g < NG; ++g){
    u32 bits = rand32(ka, kb, base + (u32)g, (u32)(NDRAWS * NPTS * NG));
    float u = u01f(bits);
    float e = -log1pf(-u);
    float kk = (float)g + 0.5f;
    sum += e / (kk * kk + c2w);
  }
  omega[idx] = sum / 19.739208802178716f;
}

__global__ void k_out(const float* mll, float* out){
  if (threadIdx.x == 0){
    float s = 0.f;
    for (int dd = 0; dd < NDRAWS; ++dd) s += mll[dd];
    float m = s / (float)NDRAWS;
    out[0] = (-m) / (float)NPTS;
  }
}

// ---------------- host-side key derivation ----------------
static void host_split(u32 ka, u32 kb, int num, u32* outA, u32* outB){
#if PARTITIONABLE
  for (int j = 0; j < num; ++j) tf2x32(ka, kb, 0u, (u32)j, &outA[j], &outB[j]);
#else
  u32 flat[40];
  for (int k = 0; k < num; ++k){
    u32 a, b; tf2x32(ka, kb, (u32)k, (u32)(num + k), &a, &b);
    flat[k] = a; flat[num + k] = b;
  }
  for (int j = 0; j < num; ++j){ outA[j] = flat[2 * j]; outB[j] = flat[2 * j + 1]; }
#endif
}

extern "C" void kernel_launch(void* const* d_in, const int* in_sizes, int n_in,
                              void* d_out, int out_size, void* d_ws, size_t ws_size,
                              hipStream_t stream){
  const float* X  = (const float*)d_in[0];
  const int*   Y  = (const int*)d_in[1];
  const float* osp = (const float*)d_in[2];
  const float* lsp = (const float*)d_in[3];
  float* out = (float*)d_out;

  const size_t NN = (size_t)NPTS * NPTS;
  char* p = (char*)d_ws;
  // ---- persistent region ----
  float* Kinvp  = (float*)p;  p += AST * 4;
  float* omega  = (float*)p;  p += (size_t)NDRAWS * NPTS * 4;
  float* fbuf   = (float*)p;  p += (size_t)NDRAWS * NPTS * 4;
  float* epsb   = (float*)p;  p += (size_t)NDRAWS * NPTS * 4;
  float* kappaf = (float*)p;  p += NPTS * 4;
  float* x2     = (float*)p;  p += NPTS * 4;
  float* mll    = (float*)p;  p += 128;
  float* ldetK  = (float*)p;  p += 128;
  uintptr_t ip = (uintptr_t)p; ip = (ip + 255) & ~(uintptr_t)255;
  char* cb = (char*)ip;

  // ---- setup-only aliases ----
  double* Ld    = (double*)cb;                                        // 8 MB
  double* Td    = (double*)(cb + NN * 8);                             // 8 MB
  double* DinvD = (double*)(cb + NN * 16);                            // 512 KB
  float*  Lf    = (float*)(cb + NN * 16 + (size_t)16 * 4096 * 8);     // 4 MB
  double* Gslc  = (double*)(cb + NN * 16 + (size_t)16 * 4096 * 8 + NN * 4);  // 7.9 MB

  // ---- chunk buffers (overlay same region): A + DI + S per draw ----
  size_t rem = ws_size - (size_t)(cb - (char*)d_ws);
  const size_t PER_DRAW = AST * 4 + (size_t)16 * 4096 * 4 * 2;
  int CH = (int)(rem / PER_DRAW);
  if (CH > NDRAWS) CH = NDRAWS;
  if (CH < 1) CH = 1;
  float* bufA  = (float*)cb;
  float* dinvF = (float*)(cb + (size_t)CH * AST * 4);
  float* sbuf  = (float*)(cb + (size_t)CH * (AST * 4 + (size_t)16 * 4096 * 4));

  // ---- keys ----
  u32 r3A[3], r3B[3];
  host_split(0u, 42u, 3, r3A, r3B);
  u32 kiA = r3A[0], kiB = r3B[0];
  u32 koA = r3A[1], koB = r3B[1];
  u32 klA = r3A[2], klB = r3B[2];
  u32 kkA[NSTEPS], kkB[NSTEPS];
  host_split(klA, klB, NSTEPS, kkA, kkB);
  u32 k1A[NSTEPS], k1B[NSTEPS], k2A[NSTEPS], k2B[NSTEPS];
  for (int t = 0; t < NSTEPS; ++t){
    u32 sA[2], sB[2];
    host_split(kkA[t], kkB[t], 2, sA, sB);
    k1A[t] = sA[0]; k1B[t] = sB[0];
    k2A[t] = sA[1]; k2B[t] = sB[1];
  }

  // ---- setup: K (f64), chol, Lf, logdet, slice-parallel trinv, packed flipped Kinv ----
  k_prep<<<dim3(4), 256, 0, stream>>>(X, Y, x2, kappaf);
  k_computeK<<<dim3(64, 64), dim3(16, 16), 0, stream>>>(X, x2, osp, lsp, Ld);
  run_chol_d(Ld, DinvD, stream);
  k_castL<<<dim3(4096), 256, 0, stream>>>(Ld, Lf);
  k_logdetK<<<dim3(1), 256, 0, stream>>>(Ld, ldetK);
  k_trinv_copy_diag<<<dim3(16), 256, 0, stream>>>(DinvD, Td);
  for (int lev = 1; lev < 16; ++lev){
    k_trinv_part<<<dim3(16 - lev, lev), 256, 0, stream>>>(Ld, Td, Gslc, lev);
    k_trinv_fin<<<dim3(16 - lev), 256, 0, stream>>>(Td, Gslc, lev);
  }
  k_syrk_kinv_flip<<<dim3(NTRI), 256, 0, stream>>>(Td, Kinvp);

  // ---- initial Gibbs state ----
  k_gen_eps<<<dim3(80), 256, 0, stream>>>(kiA, kiB, epsb);
  k_init_f2<<<dim3(16, NDRAWS), 256, 0, stream>>>(Lf, epsb, fbuf);
  k_pg<<<dim3(80), 256, 0, stream>>>(koA, koB, fbuf, omega);

  // ---- Gibbs steps: 17 launches per (step, chunk) ----
  for (int t = 0; t < NSTEPS; ++t){
    for (int c0 = 0; c0 < NDRAWS; c0 += CH){
      int nb = NDRAWS - c0 < CH ? NDRAWS - c0 : CH;
      k_stage0<<<dim3(544 * nb + nb + nb * 4), 256, 0, stream>>>(
          Kinvp, omega, bufA, dinvF, sbuf, epsb, c0, nb, 0, 1, k1A[t], k1B[t]);
      for (int pp = 0; pp < 15; ++pp){
        int nr = 15 - pp;
        int npair = nr * (nr + 1) / 2;
        k_updstage<<<dim3(npair * nb), 256, 0, stream>>>(bufA, dinvF, sbuf, pp, npair);
      }
      k_solve_pg<<<dim3(nb), 256, 0, stream>>>(bufA, dinvF, kappaf, epsb, omega,
                                               c0, k2A[t], k2B[t]);
    }
  }

  // ---- final mll (Woodbury) ----
  for (int c0 = 0; c0 < NDRAWS; c0 += CH){
    int nb = NDRAWS - c0 < CH ? NDRAWS - c0 : CH;
    k_stage0<<<dim3(544 * nb + nb), 256, 0, stream>>>(
        Kinvp, omega, bufA, dinvF, sbuf, epsb, c0, nb, 1, 0, 0u, 0u);
    for (int pp = 0; pp < 15; ++pp){
      int nr = 15 - pp;
      int npair = nr * (nr + 1) / 2;
      k_updstage<<<dim3(npair * nb), 256, 0, stream>>>(bufA, dinvF, sbuf, pp, npair);
    }
    k_final_w<<<dim3(nb), 256, 0, stream>>>(bufA, dinvF, kappaf, ldetK, mll, c0);
  }
  k_out<<<dim3(1), 64, 0, stream>>>(mll, out);
}